// Round 5
// baseline (541.814 us; speedup 1.0000x reference)
//
#include <hip/hip_runtime.h>
#include <hip/hip_bf16.h>
#include <math.h>

// Problem constants (fixed shapes)
#define SS   2048   // sequence length
#define EE   2048   // embed dim
#define HH   16     // heads
#define QLAT 1536   // q latent
#define KLAT 512    // kv latent
#define DN   128
#define DR   64
#define DV   128
#define DQ   192    // DN+DR
#define KVD  256    // DN+DV
#define CKVW 576    // KLAT+DR
#define QW   3072   // HH*DQ
#define KVW  4096   // HH*KVD
#define OW   2048   // HH*DV

#define NSEG 4      // key segments (flash-decoding split)
#define SEGK 512    // keys per segment
#define PT_STRIDE 72

typedef __attribute__((ext_vector_type(8))) short short8;
typedef __attribute__((ext_vector_type(4))) float f32x4;

// ---------------- helpers ----------------
__global__ void detect_dtype(const unsigned int* __restrict__ lnw, int* flag) {
    *flag = (lnw[0] == 0x3F803F80u) ? 1 : 0;  // bf16 pair of 1.0 vs fp32 1.0
}

__device__ __forceinline__ float ld_in(const void* p, size_t i, int bf) {
    if (bf) return __bfloat162float(((const __hip_bfloat16*)p)[i]);
    return ((const float*)p)[i];
}

__device__ __forceinline__ ushort f2b(float v) {
    __hip_bfloat16 b = __float2bfloat16(v);
    return *(ushort*)&b;
}
__device__ __forceinline__ float b2f(ushort u) {
    __hip_bfloat16 b = *(__hip_bfloat16*)&u;
    return __bfloat162float(b);
}

// async global->LDS, 16 B per lane; LDS dst must be wave-uniform base + lane*16
__device__ __forceinline__ void async16(const ushort* g, ushort* l) {
    __builtin_amdgcn_global_load_lds(
        (const __attribute__((address_space(1))) void*)g,
        (__attribute__((address_space(3))) void*)l, 16, 0, 0);
}

// ---------------- input convert (x -> bf16) ----------------
__global__ __launch_bounds__(256) void conv_x_bf(
    const void* __restrict__ src, ushort* __restrict__ dst, int n, const int* flag) {
    const int bf = *flag;
    int i = (blockIdx.x * 256 + threadIdx.x) * 4;
    if (i >= n) return;
    ushort4 u;
    u.x = f2b(ld_in(src, i + 0, bf));
    u.y = f2b(ld_in(src, i + 1, bf));
    u.z = f2b(ld_in(src, i + 2, bf));
    u.w = f2b(ld_in(src, i + 3, bf));
    *(ushort4*)(dst + i) = u;
}

// ---------------- weight transpose+convert: in[R][C] -> out[C][R] bf16 ----------------
__global__ __launch_bounds__(256) void transpose_bf(
    const void* __restrict__ in, ushort* __restrict__ out,
    int R, int C, const int* flag) {
    const int bf = *flag;
    __shared__ ushort t[32][33];
    const int c0 = blockIdx.x * 32, r0 = blockIdx.y * 32;
    const int tx = threadIdx.x & 31, ty = threadIdx.x >> 5;
    #pragma unroll
    for (int j = 0; j < 4; ++j)
        t[ty + j * 8][tx] = f2b(ld_in(in, (size_t)(r0 + ty + j * 8) * C + c0 + tx, bf));
    __syncthreads();
    #pragma unroll
    for (int j = 0; j < 4; ++j)
        out[(size_t)(c0 + ty + j * 8) * R + r0 + tx] = t[tx][ty + j * 8];
}

// ---------------- bf16 MFMA GEMM: C[M][N] = A[M][K] @ Bt[N][K]^T ----------------
// XOR-swizzled LDS: 16B part p of row r stored at p^((r>>1)&3) -> b128 frag
// reads hit all 32 banks (was 16).
__global__ __launch_bounds__(256) void gemm_bf(
    const ushort* __restrict__ A, const ushort* __restrict__ Bt,
    void* __restrict__ C, int N, int K, int lda, int ldb, int ldc,
    int cmode, const int* __restrict__ cflag) {
    __shared__ ushort As[128 * 32];
    __shared__ ushort Bs[128 * 32];
    const int tid = threadIdx.x;
    const int bm = blockIdx.y * 128, bn = blockIdx.x * 128;
    const int lane = tid & 63, wv = tid >> 6;
    const int wm = (wv & 1) * 64, wn = (wv >> 1) * 64;
    const int ln = lane & 15, quad = lane >> 4;

    f32x4 acc[4][4];
    #pragma unroll
    for (int i = 0; i < 4; ++i)
        #pragma unroll
        for (int j = 0; j < 4; ++j) acc[i][j] = (f32x4){0.f, 0.f, 0.f, 0.f};

    const int srow = tid >> 2;
    const int spart = (((tid & 3) ^ ((tid >> 3) & 3))) * 8;  // swizzled source 16B part
    const ushort* Ag0 = A  + (size_t)(bm + srow) * lda + spart;
    const ushort* Ag1 = Ag0 + (size_t)64 * lda;
    const ushort* Bg0 = Bt + (size_t)(bn + srow) * ldb + spart;
    const ushort* Bg1 = Bg0 + (size_t)64 * ldb;
    ushort* Asl = As + tid * 8;
    ushort* Bsl = Bs + tid * 8;
    const bool bok0 = (bn + srow) < N;
    const bool bok1 = (bn + 64 + srow) < N;
    const int swq = (quad ^ ((ln >> 1) & 3)) * 8;  // swizzled read part

    for (int k0 = 0; k0 < K; k0 += 32) {
        async16(Ag0 + k0, Asl);
        async16(Ag1 + k0, Asl + 2048);
        if (bok0) async16(Bg0 + k0, Bsl);
        if (bok1) async16(Bg1 + k0, Bsl + 2048);
        __syncthreads();
        short8 af[4], bfr[4];
        #pragma unroll
        for (int t = 0; t < 4; ++t) {
            af[t]  = *(const short8*)&As[(wm + t * 16 + ln) * 32 + swq];
            bfr[t] = *(const short8*)&Bs[(wn + t * 16 + ln) * 32 + swq];
        }
        #pragma unroll
        for (int i = 0; i < 4; ++i)
            #pragma unroll
            for (int j = 0; j < 4; ++j)
                acc[i][j] = __builtin_amdgcn_mfma_f32_16x16x32_bf16(af[i], bfr[j], acc[i][j], 0, 0, 0);
        __syncthreads();
    }

    const int cbf = (cmode == 2) ? *cflag : cmode;
    #pragma unroll
    for (int i = 0; i < 4; ++i) {
        #pragma unroll
        for (int r = 0; r < 4; ++r) {
            const int m = bm + wm + i * 16 + quad * 4 + r;
            #pragma unroll
            for (int j = 0; j < 4; ++j) {
                const int n = bn + wn + j * 16 + ln;
                if (n < N) {
                    if (cbf) ((ushort*)C)[(size_t)m * ldc + n] = f2b(acc[i][j][r]);
                    else     ((float*)C)[(size_t)m * ldc + n] = acc[i][j][r];
                }
            }
        }
    }
}

// ---------------- RMSNorm bf16 in-place (fp32 math) ----------------
__global__ __launch_bounds__(256) void rmsnorm_bf(
    ushort* __restrict__ x, const void* __restrict__ w,
    int cols, int stride, const int* wflag) {
    const int wbf = *wflag;
    ushort* p = x + (size_t)blockIdx.x * stride;
    float ss = 0.f;
    for (int i = threadIdx.x; i < cols; i += 256) { float v = b2f(p[i]); ss += v * v; }
    #pragma unroll
    for (int off = 32; off; off >>= 1) ss += __shfl_xor(ss, off);
    __shared__ float red[4];
    const int wid = threadIdx.x >> 6, lane = threadIdx.x & 63;
    if (lane == 0) red[wid] = ss;
    __syncthreads();
    const float tot = red[0] + red[1] + red[2] + red[3];
    const float scale = rsqrtf(tot / (float)cols + 1e-6f);
    for (int i = threadIdx.x; i < cols; i += 256)
        p[i] = f2b(b2f(p[i]) * scale * ld_in(w, i, wbf));
}

// ---------------- RoPE (fp32 math on bf16 data) ----------------
__device__ __forceinline__ void rope64(const float* in, float t, float* out) {
    #pragma unroll
    for (int i = 0; i < 32; ++i) {
        float inv = powf(10000.0f, -(float)i / 32.0f);
        float sv, cv;
        sincosf(t * inv, &sv, &cv);
        float x0 = in[2 * i], x1 = in[2 * i + 1];
        out[i]      = x0 * cv - x1 * sv;
        out[i + 32] = x1 * cv + x0 * sv;
    }
}

__global__ void rope_q_bf(ushort* __restrict__ q) {
    int idx = blockIdx.x * blockDim.x + threadIdx.x;
    if (idx >= SS * HH) return;
    int s = idx >> 4, h = idx & 15;
    ushort* p = q + (size_t)s * QW + h * DQ + DN;
    float buf[DR], out[DR];
    #pragma unroll
    for (int i = 0; i < DR; ++i) buf[i] = b2f(p[i]);
    rope64(buf, (float)s, out);
    #pragma unroll
    for (int i = 0; i < DR; ++i) p[i] = f2b(out[i]);
}

__global__ void rope_k_bf(const ushort* __restrict__ ckv, ushort* __restrict__ kpe) {
    int s = blockIdx.x * blockDim.x + threadIdx.x;
    if (s >= SS) return;
    const ushort* p = ckv + (size_t)s * CKVW + KLAT;
    float buf[DR], out[DR];
    #pragma unroll
    for (int i = 0; i < DR; ++i) buf[i] = b2f(p[i]);
    rope64(buf, (float)s, out);
    ushort* dp = kpe + (size_t)s * DR;
    #pragma unroll
    for (int i = 0; i < DR; ++i) dp[i] = f2b(out[i]);
}

// ---------------- build head-major K-full: kf[h][s][192] ----------------
__global__ __launch_bounds__(256) void build_kf(
    const ushort* __restrict__ kv, const ushort* __restrict__ kpe,
    ushort* __restrict__ kf) {
    int idx = blockIdx.x * 256 + threadIdx.x;       // SS*HH*24 items
    int part = idx % 24;
    int rest = idx / 24;
    int h = rest & 15, s = rest >> 4;
    short8 v;
    if (part < 16) v = *(const short8*)(kv + (size_t)s * KVW + h * KVD + part * 8);
    else           v = *(const short8*)(kpe + (size_t)s * DR + (part - 16) * 8);
    *(short8*)(kf + ((size_t)h * SS + s) * 192 + part * 8) = v;
}

// ---------------- build V^T: vt[h][d][s] ----------------
__global__ __launch_bounds__(256) void build_vt(
    const ushort* __restrict__ kv, ushort* __restrict__ vt) {
    __shared__ ushort tile[32][33];
    const int s0 = blockIdx.x * 32, d0 = blockIdx.y * 32, h = blockIdx.z;
    const int tx = threadIdx.x & 31, ty = threadIdx.x >> 5;
    #pragma unroll
    for (int j = 0; j < 4; ++j)
        tile[ty + j * 8][tx] = kv[(size_t)(s0 + ty + j * 8) * KVW + h * KVD + DN + d0 + tx];
    __syncthreads();
    #pragma unroll
    for (int j = 0; j < 4; ++j)
        vt[((size_t)h * DV + d0 + ty + j * 8) * SS + s0 + tx] = tile[tx][ty + j * 8];
}

// ---------------- split-K MFMA flash attention ----------------
// grid (seg, bq(reversed), h); block = 4 waves x 16 q-rows; 64-key chunks.
// K staged in swizzled LDS; V B-frags loaded directly from global vt (L1-resident).
__global__ __launch_bounds__(256, 4) void attn_mfma2(
    const ushort* __restrict__ qbf, const ushort* __restrict__ kf,
    const ushort* __restrict__ vt, ushort* __restrict__ opart,
    float* __restrict__ ml) {
    const int seg = blockIdx.x, bq = 31 - blockIdx.y, h = blockIdx.z;
    if ((seg << 3) > bq) return;   // causal: segment starts beyond q-tile

    __shared__ ushort Kt[6 * 64 * 32];           // 24576 B
    __shared__ ushort Pt[4][16 * PT_STRIDE];     // 9216 B

    const int tid = threadIdx.x, lane = tid & 63, wl = tid >> 6;
    const int ln = lane & 15, quad = lane >> 4;
    const int qw = bq * 64 + wl * 16;
    const int kstart = seg * SEGK;
    const int kend = min(kstart + SEGK, bq * 64 + 64);
    const int nch = (kend - kstart) >> 6;
    const float scale = 0.07216878364870322f;  // 1/sqrt(192)

    short8 aq[6];
    const ushort* qrow = qbf + (size_t)(qw + ln) * QW + h * DQ;
    #pragma unroll
    for (int kb = 0; kb < 6; ++kb)
        aq[kb] = *(const short8*)(qrow + kb * 32 + quad * 8);

    const ushort* kfh = kf + (size_t)h * SS * 192;
    const ushort* vth = vt + (size_t)h * DV * SS;

    // K staging: key = tid>>2, 16B part = tid&3 (xor-swizzled at source), kb = i
    const int key_s = tid >> 2;
    const int swp = ((tid & 3) ^ ((tid >> 3) & 3)) * 8;
    const ushort* kg = kfh + (size_t)(kstart + key_s) * 192 + swp;
    ushort* kdst = Kt + tid * 8;
    const int swq = (quad ^ ((ln >> 1) & 3)) * 8;   // swizzled read part
    const ushort* vbase = vth + (size_t)ln * SS + quad * 8;

    f32x4 oacc[8];
    #pragma unroll
    for (int f = 0; f < 8; ++f) oacc[f] = (f32x4){0.f, 0.f, 0.f, 0.f};
    float mrow[4] = {-INFINITY, -INFINITY, -INFINITY, -INFINITY};
    float lrow[4] = {0.f, 0.f, 0.f, 0.f};

    for (int c = 0; c < nch; ++c) {
        const int k0 = kstart + (c << 6);
        #pragma unroll
        for (int i = 0; i < 6; ++i)
            async16(kg + i * 32, kdst + i * 2048);
        kg += 64 * 192;
        __syncthreads();

        if (k0 <= qw + 15) {
            // ---- S = Q K^T (4 n-subtiles x 6 k-blocks) ----
            f32x4 s[4];
            #pragma unroll
            for (int ns = 0; ns < 4; ++ns) s[ns] = (f32x4){0.f, 0.f, 0.f, 0.f};
            #pragma unroll
            for (int ns = 0; ns < 4; ++ns)
                #pragma unroll
                for (int kb = 0; kb < 6; ++kb) {
                    short8 bk = *(const short8*)&Kt[(kb * 64 + ns * 16 + ln) * 32 + swq];
                    s[ns] = __builtin_amdgcn_mfma_f32_16x16x32_bf16(aq[kb], bk, s[ns], 0, 0, 0);
                }
            // ---- V frags for kb2=0 issued early (latency overlaps softmax) ----
            short8 bv0[8];
            #pragma unroll
            for (int nb = 0; nb < 8; ++nb)
                bv0[nb] = *(const short8*)(vbase + (size_t)(nb * 16) * SS + k0);
            // ---- mask + online softmax (row = quad*4+r, col = ns*16+ln) ----
            float pv[4][4], rmax[4];
            #pragma unroll
            for (int r = 0; r < 4; ++r) rmax[r] = -1e30f;
            #pragma unroll
            for (int ns = 0; ns < 4; ++ns)
                #pragma unroll
                for (int r = 0; r < 4; ++r) {
                    int key = k0 + ns * 16 + ln;
                    int qr = qw + quad * 4 + r;
                    float v = s[ns][r] * scale;
                    if (key > qr) v = -1e30f;
                    pv[ns][r] = v;
                    rmax[r] = fmaxf(rmax[r], v);
                }
            #pragma unroll
            for (int off = 8; off; off >>= 1)
                #pragma unroll
                for (int r = 0; r < 4; ++r)
                    rmax[r] = fmaxf(rmax[r], __shfl_xor(rmax[r], off));
            float alpha[4], psum[4];
            #pragma unroll
            for (int r = 0; r < 4; ++r) {
                float mnew = fmaxf(mrow[r], rmax[r]);
                alpha[r] = __expf(mrow[r] - mnew);
                mrow[r] = mnew;
            }
            #pragma unroll
            for (int ns = 0; ns < 4; ++ns)
                #pragma unroll
                for (int r = 0; r < 4; ++r)
                    pv[ns][r] = __expf(pv[ns][r] - mrow[r]);
            #pragma unroll
            for (int r = 0; r < 4; ++r)
                psum[r] = (pv[0][r] + pv[1][r]) + (pv[2][r] + pv[3][r]);
            #pragma unroll
            for (int off = 8; off; off >>= 1)
                #pragma unroll
                for (int r = 0; r < 4; ++r)
                    psum[r] += __shfl_xor(psum[r], off);
            #pragma unroll
            for (int r = 0; r < 4; ++r) lrow[r] = lrow[r] * alpha[r] + psum[r];
            #pragma unroll
            for (int f = 0; f < 8; ++f)
                #pragma unroll
                for (int r = 0; r < 4; ++r) oacc[f][r] *= alpha[r];
            // ---- P -> LDS (per-wave, row-major [row][key], stride 72) ----
            #pragma unroll
            for (int ns = 0; ns < 4; ++ns)
                #pragma unroll
                for (int r = 0; r < 4; ++r)
                    Pt[wl][(quad * 4 + r) * PT_STRIDE + ns * 16 + ln] = f2b(pv[ns][r]);
            // ---- V frags for kb2=1 ----
            short8 bv1[8];
            #pragma unroll
            for (int nb = 0; nb < 8; ++nb)
                bv1[nb] = *(const short8*)(vbase + (size_t)(nb * 16) * SS + k0 + 32);
            // ---- O += P V ----
            short8 pa0 = *(const short8*)&Pt[wl][ln * PT_STRIDE + quad * 8];
            short8 pa1 = *(const short8*)&Pt[wl][ln * PT_STRIDE + 32 + quad * 8];
            #pragma unroll
            for (int nb = 0; nb < 8; ++nb)
                oacc[nb] = __builtin_amdgcn_mfma_f32_16x16x32_bf16(pa0, bv0[nb], oacc[nb], 0, 0, 0);
            #pragma unroll
            for (int nb = 0; nb < 8; ++nb)
                oacc[nb] = __builtin_amdgcn_mfma_f32_16x16x32_bf16(pa1, bv1[nb], oacc[nb], 0, 0, 0);
        }
        __syncthreads();
    }

    // ---- store unnormalized partial O (bf16) + m,l ----
    const size_t pbase = (((size_t)h * 32 + bq) * NSEG + seg) * 64;
    #pragma unroll
    for (int nb = 0; nb < 8; ++nb)
        #pragma unroll
        for (int r = 0; r < 4; ++r)
            opart[(pbase + wl * 16 + quad * 4 + r) * 128 + nb * 16 + ln] = f2b(oacc[nb][r]);
    if (ln == 0) {
        #pragma unroll
        for (int r = 0; r < 4; ++r) {
            ml[(pbase + wl * 16 + quad * 4 + r) * 2]     = mrow[r];
            ml[(pbase + wl * 16 + quad * 4 + r) * 2 + 1] = lrow[r];
        }
    }
}

// ---------------- merge partials -> obf ----------------
__global__ __launch_bounds__(256) void merge_attn(
    const ushort* __restrict__ opart, const float* __restrict__ ml,
    ushort* __restrict__ obf) {
    const int q = blockIdx.x;
    const int bq = q >> 6, row = q & 63, smax = bq >> 3;
    const int t = threadIdx.x;
    #pragma unroll
    for (int pp = 0; pp < 8; ++pp) {
        int idx = pp * 256 + t;            // 0..2047 = h*128 + d
        int h = idx >> 7, d = idx & 127;
        size_t rbase = (((size_t)h * 32 + bq) * NSEG) * 64 + row;  // + s*64
        float M = -1e30f;
        for (int s = 0; s <= smax; ++s)
            M = fmaxf(M, ml[(rbase + (size_t)s * 64) * 2]);
        float L = 0.f, acc = 0.f;
        for (int s = 0; s <= smax; ++s) {
            size_t ri = rbase + (size_t)s * 64;
            float w = __expf(ml[ri * 2] - M);
            L += w * ml[ri * 2 + 1];
            acc += w * b2f(opart[ri * 128 + d]);
        }
        obf[(size_t)q * OW + h * DV + d] = f2b(acc / L);
    }
}

// ---------------- launch ----------------
extern "C" void kernel_launch(void* const* d_in, const int* in_sizes, int n_in,
                              void* d_out, int out_size, void* d_ws, size_t ws_size,
                              hipStream_t stream) {
    const void* x       = d_in[0];
    const void* w_q_a   = d_in[1];
    const void* q_a_ln  = d_in[2];
    const void* w_q_b   = d_in[3];
    const void* w_kv_a  = d_in[4];
    const void* kv_a_ln = d_in[5];
    const void* w_kv_b  = d_in[6];
    const void* w_out   = d_in[7];

    char* ws = (char*)d_ws;
    int*    flag  = (int*)ws;
    ushort* qbf   = (ushort*)(ws + 256);             // S*QW
    ushort* obf   = qbf   + (size_t)SS * QW;         // S*OW
    ushort* wqat  = obf   + (size_t)SS * OW;         // QLAT*EE
    ushort* wkvat = wqat  + (size_t)QLAT * EE;       // CKVW*EE
    ushort* wqbt  = wkvat + (size_t)CKVW * EE;       // QW*QLAT
    ushort* wkvbt = wqbt  + (size_t)QW * QLAT;       // KVW*KLAT
    ushort* woutt = wkvbt + (size_t)KVW * KLAT;      // EE*OW
    ushort* kf    = woutt + (size_t)EE * OW;         // HH*SS*192
    ushort* vt    = kf    + (size_t)HH * SS * 192;   // HH*DV*SS
    float*  ml    = (float*)(vt + (size_t)HH * DV * SS);  // HH*32*NSEG*64*2 floats
    // overlay zone (all dead before attention writes opart):
    ushort* ckvbf = (ushort*)(ml + (size_t)HH * 32 * NSEG * 64 * 2);  // S*CKVW
    ushort* qa_bf = ckvbf + (size_t)SS * CKVW;       // S*QLAT
    ushort* xbf   = qa_bf + (size_t)SS * QLAT;       // S*EE
    ushort* kvbf  = xbf   + (size_t)SS * EE;         // S*KVW
    ushort* kpebf = kvbf  + (size_t)SS * KVW;        // S*DR
    ushort* opart = ckvbf;  // HH*32*NSEG*64*128 halfs <= overlay span (17.04M)

    detect_dtype<<<1, 1, 0, stream>>>((const unsigned int*)q_a_ln, flag);

    conv_x_bf<<<(SS * EE / 4 + 255) / 256, 256, 0, stream>>>(x, xbf, SS * EE, flag);
    transpose_bf<<<dim3(QLAT / 32, EE / 32), 256, 0, stream>>>(w_q_a, wqat, EE, QLAT, flag);
    transpose_bf<<<dim3(CKVW / 32, EE / 32), 256, 0, stream>>>(w_kv_a, wkvat, EE, CKVW, flag);
    transpose_bf<<<dim3(QW / 32, QLAT / 32), 256, 0, stream>>>(w_q_b, wqbt, QLAT, QW, flag);
    transpose_bf<<<dim3(KVW / 32, KLAT / 32), 256, 0, stream>>>(w_kv_b, wkvbt, KLAT, KVW, flag);
    transpose_bf<<<dim3(EE / 32, OW / 32), 256, 0, stream>>>(w_out, woutt, OW, EE, flag);

    // qa_bf = x @ w_q_a  (2048x1536, K=2048)
    gemm_bf<<<dim3(QLAT / 128, SS / 128), 256, 0, stream>>>(
        xbf, wqat, qa_bf, QLAT, EE, EE, EE, QLAT, 1, nullptr);
    // ckvbf = x @ w_kv_a (2048x576, K=2048)
    gemm_bf<<<dim3((CKVW + 127) / 128, SS / 128), 256, 0, stream>>>(
        xbf, wkvat, ckvbf, CKVW, EE, EE, EE, CKVW, 1, nullptr);

    rmsnorm_bf<<<SS, 256, 0, stream>>>(qa_bf, q_a_ln, QLAT, QLAT, flag);
    rmsnorm_bf<<<SS, 256, 0, stream>>>(ckvbf, kv_a_ln, KLAT, CKVW, flag);

    // qbf = qa_norm @ w_q_b (2048x3072, K=1536)
    gemm_bf<<<dim3(QW / 128, SS / 128), 256, 0, stream>>>(
        qa_bf, wqbt, qbf, QW, QLAT, QLAT, QLAT, QW, 1, nullptr);
    // kvbf = ckv_norm @ w_kv_b (2048x4096, K=512)
    gemm_bf<<<dim3(KVW / 128, SS / 128), 256, 0, stream>>>(
        ckvbf, wkvbt, kvbf, KVW, KLAT, CKVW, KLAT, KVW, 1, nullptr);

    rope_q_bf<<<(SS * HH + 255) / 256, 256, 0, stream>>>(qbf);
    rope_k_bf<<<(SS + 63) / 64, 64, 0, stream>>>(ckvbf, kpebf);

    build_kf<<<SS * HH * 24 / 256, 256, 0, stream>>>(kvbf, kpebf, kf);
    build_vt<<<dim3(SS / 32, DV / 32, HH), 256, 0, stream>>>(kvbf, vt);

    attn_mfma2<<<dim3(NSEG, SS / 64, HH), 256, 0, stream>>>(qbf, kf, vt, opart, ml);
    merge_attn<<<SS, 256, 0, stream>>>(opart, ml, obf);

    // out = o @ w_out (2048x2048, K=2048)
    gemm_bf<<<dim3(EE / 128, SS / 128), 256, 0, stream>>>(
        obf, woutt, d_out, EE, OW, OW, OW, EE, 2, flag);
}

// Round 6
// 477.723 us; speedup vs baseline: 1.1342x; 1.1342x over previous
//
#include <hip/hip_runtime.h>
#include <hip/hip_bf16.h>
#include <math.h>

// Problem constants (fixed shapes)
#define SS   2048   // sequence length
#define EE   2048   // embed dim
#define HH   16     // heads
#define QLAT 1536   // q latent
#define KLAT 512    // kv latent
#define DN   128
#define DR   64
#define DV   128
#define DQ   192    // DN+DR
#define KVD  256    // DN+DV
#define CKVW 576    // KLAT+DR
#define QW   3072   // HH*DQ
#define KVW  4096   // HH*KVD
#define OW   2048   // HH*DV

#define NSEG 4      // key segments (flash-decoding split)
#define SEGK 512    // keys per segment
#define PT_STRIDE 72

typedef __attribute__((ext_vector_type(8))) short short8;
typedef __attribute__((ext_vector_type(4))) float f32x4;

// ---------------- helpers ----------------
__global__ void detect_dtype(const unsigned int* __restrict__ lnw, int* flag) {
    *flag = (lnw[0] == 0x3F803F80u) ? 1 : 0;  // bf16 pair of 1.0 vs fp32 1.0
}

__device__ __forceinline__ float ld_in(const void* p, size_t i, int bf) {
    if (bf) return __bfloat162float(((const __hip_bfloat16*)p)[i]);
    return ((const float*)p)[i];
}

__device__ __forceinline__ ushort f2b(float v) {
    __hip_bfloat16 b = __float2bfloat16(v);
    return *(ushort*)&b;
}
__device__ __forceinline__ float b2f(ushort u) {
    __hip_bfloat16 b = *(__hip_bfloat16*)&u;
    return __bfloat162float(b);
}

// async global->LDS, 16 B per lane; LDS dst must be wave-uniform base + lane*16
__device__ __forceinline__ void async16(const ushort* g, ushort* l) {
    __builtin_amdgcn_global_load_lds(
        (const __attribute__((address_space(1))) void*)g,
        (__attribute__((address_space(3))) void*)l, 16, 0, 0);
}

// ---------------- input convert (x -> bf16) ----------------
__global__ __launch_bounds__(256) void conv_x_bf(
    const void* __restrict__ src, ushort* __restrict__ dst, int n, const int* flag) {
    const int bf = *flag;
    int i = (blockIdx.x * 256 + threadIdx.x) * 4;
    if (i >= n) return;
    ushort4 u;
    u.x = f2b(ld_in(src, i + 0, bf));
    u.y = f2b(ld_in(src, i + 1, bf));
    u.z = f2b(ld_in(src, i + 2, bf));
    u.w = f2b(ld_in(src, i + 3, bf));
    *(ushort4*)(dst + i) = u;
}

// ---------------- weight transpose+convert: in[R][C] -> out[C][R] bf16 ----------------
__global__ __launch_bounds__(256) void transpose_bf(
    const void* __restrict__ in, ushort* __restrict__ out,
    int R, int C, const int* flag) {
    const int bf = *flag;
    __shared__ ushort t[32][33];
    const int c0 = blockIdx.x * 32, r0 = blockIdx.y * 32;
    const int tx = threadIdx.x & 31, ty = threadIdx.x >> 5;
    #pragma unroll
    for (int j = 0; j < 4; ++j)
        t[ty + j * 8][tx] = f2b(ld_in(in, (size_t)(r0 + ty + j * 8) * C + c0 + tx, bf));
    __syncthreads();
    #pragma unroll
    for (int j = 0; j < 4; ++j)
        out[(size_t)(c0 + ty + j * 8) * R + r0 + tx] = t[tx][ty + j * 8];
}

// ---------------- bf16 MFMA GEMM: C[M][N] = A[M][K] @ Bt[N][K]^T ----------------
// XOR-swizzled LDS: 16B part p of row r stored at p^((r>>1)&3) -> b128 frag
// reads hit all 32 banks.
__global__ __launch_bounds__(256) void gemm_bf(
    const ushort* __restrict__ A, const ushort* __restrict__ Bt,
    void* __restrict__ C, int N, int K, int lda, int ldb, int ldc,
    int cmode, const int* __restrict__ cflag) {
    __shared__ ushort As[128 * 32];
    __shared__ ushort Bs[128 * 32];
    const int tid = threadIdx.x;
    const int bm = blockIdx.y * 128, bn = blockIdx.x * 128;
    const int lane = tid & 63, wv = tid >> 6;
    const int wm = (wv & 1) * 64, wn = (wv >> 1) * 64;
    const int ln = lane & 15, quad = lane >> 4;

    f32x4 acc[4][4];
    #pragma unroll
    for (int i = 0; i < 4; ++i)
        #pragma unroll
        for (int j = 0; j < 4; ++j) acc[i][j] = (f32x4){0.f, 0.f, 0.f, 0.f};

    const int srow = tid >> 2;
    const int spart = (((tid & 3) ^ ((tid >> 3) & 3))) * 8;  // swizzled source 16B part
    const ushort* Ag0 = A  + (size_t)(bm + srow) * lda + spart;
    const ushort* Ag1 = Ag0 + (size_t)64 * lda;
    const ushort* Bg0 = Bt + (size_t)(bn + srow) * ldb + spart;
    const ushort* Bg1 = Bg0 + (size_t)64 * ldb;
    ushort* Asl = As + tid * 8;
    ushort* Bsl = Bs + tid * 8;
    const bool bok0 = (bn + srow) < N;
    const bool bok1 = (bn + 64 + srow) < N;
    const int swq = (quad ^ ((ln >> 1) & 3)) * 8;  // swizzled read part

    for (int k0 = 0; k0 < K; k0 += 32) {
        async16(Ag0 + k0, Asl);
        async16(Ag1 + k0, Asl + 2048);
        if (bok0) async16(Bg0 + k0, Bsl);
        if (bok1) async16(Bg1 + k0, Bsl + 2048);
        __syncthreads();
        short8 af[4], bfr[4];
        #pragma unroll
        for (int t = 0; t < 4; ++t) {
            af[t]  = *(const short8*)&As[(wm + t * 16 + ln) * 32 + swq];
            bfr[t] = *(const short8*)&Bs[(wn + t * 16 + ln) * 32 + swq];
        }
        #pragma unroll
        for (int i = 0; i < 4; ++i)
            #pragma unroll
            for (int j = 0; j < 4; ++j)
                acc[i][j] = __builtin_amdgcn_mfma_f32_16x16x32_bf16(af[i], bfr[j], acc[i][j], 0, 0, 0);
        __syncthreads();
    }

    const int cbf = (cmode == 2) ? *cflag : cmode;
    #pragma unroll
    for (int i = 0; i < 4; ++i) {
        #pragma unroll
        for (int r = 0; r < 4; ++r) {
            const int m = bm + wm + i * 16 + quad * 4 + r;
            #pragma unroll
            for (int j = 0; j < 4; ++j) {
                const int n = bn + wn + j * 16 + ln;
                if (n < N) {
                    if (cbf) ((ushort*)C)[(size_t)m * ldc + n] = f2b(acc[i][j][r]);
                    else     ((float*)C)[(size_t)m * ldc + n] = acc[i][j][r];
                }
            }
        }
    }
}

// ---------------- RMSNorm bf16 in-place (fp32 math) ----------------
__global__ __launch_bounds__(256) void rmsnorm_bf(
    ushort* __restrict__ x, const void* __restrict__ w,
    int cols, int stride, const int* wflag) {
    const int wbf = *wflag;
    ushort* p = x + (size_t)blockIdx.x * stride;
    float ss = 0.f;
    for (int i = threadIdx.x; i < cols; i += 256) { float v = b2f(p[i]); ss += v * v; }
    #pragma unroll
    for (int off = 32; off; off >>= 1) ss += __shfl_xor(ss, off);
    __shared__ float red[4];
    const int wid = threadIdx.x >> 6, lane = threadIdx.x & 63;
    if (lane == 0) red[wid] = ss;
    __syncthreads();
    const float tot = red[0] + red[1] + red[2] + red[3];
    const float scale = rsqrtf(tot / (float)cols + 1e-6f);
    for (int i = threadIdx.x; i < cols; i += 256)
        p[i] = f2b(b2f(p[i]) * scale * ld_in(w, i, wbf));
}

// ---------------- RoPE (fp32 math on bf16 data) ----------------
__device__ __forceinline__ void rope64(const float* in, float t, float* out) {
    #pragma unroll
    for (int i = 0; i < 32; ++i) {
        float inv = powf(10000.0f, -(float)i / 32.0f);
        float sv, cv;
        sincosf(t * inv, &sv, &cv);
        float x0 = in[2 * i], x1 = in[2 * i + 1];
        out[i]      = x0 * cv - x1 * sv;
        out[i + 32] = x1 * cv + x0 * sv;
    }
}

__global__ void rope_q_bf(ushort* __restrict__ q) {
    int idx = blockIdx.x * blockDim.x + threadIdx.x;
    if (idx >= SS * HH) return;
    int s = idx >> 4, h = idx & 15;
    ushort* p = q + (size_t)s * QW + h * DQ + DN;
    float buf[DR], out[DR];
    #pragma unroll
    for (int i = 0; i < DR; ++i) buf[i] = b2f(p[i]);
    rope64(buf, (float)s, out);
    #pragma unroll
    for (int i = 0; i < DR; ++i) p[i] = f2b(out[i]);
}

__global__ void rope_k_bf(const ushort* __restrict__ ckv, ushort* __restrict__ kpe) {
    int s = blockIdx.x * blockDim.x + threadIdx.x;
    if (s >= SS) return;
    const ushort* p = ckv + (size_t)s * CKVW + KLAT;
    float buf[DR], out[DR];
    #pragma unroll
    for (int i = 0; i < DR; ++i) buf[i] = b2f(p[i]);
    rope64(buf, (float)s, out);
    ushort* dp = kpe + (size_t)s * DR;
    #pragma unroll
    for (int i = 0; i < DR; ++i) dp[i] = f2b(out[i]);
}

// ---------------- build head-major K-full: kf[h][s][192] ----------------
__global__ __launch_bounds__(256) void build_kf(
    const ushort* __restrict__ kv, const ushort* __restrict__ kpe,
    ushort* __restrict__ kf) {
    int idx = blockIdx.x * 256 + threadIdx.x;       // SS*HH*24 items
    int part = idx % 24;
    int rest = idx / 24;
    int h = rest & 15, s = rest >> 4;
    short8 v;
    if (part < 16) v = *(const short8*)(kv + (size_t)s * KVW + h * KVD + part * 8);
    else           v = *(const short8*)(kpe + (size_t)s * DR + (part - 16) * 8);
    *(short8*)(kf + ((size_t)h * SS + s) * 192 + part * 8) = v;
}

// ---------------- build frag-ordered V: vt2[h][ck][idx2=kb2*8+nb][lane][8] ----------------
// Each (h,ck,idx2) frag is 1 KB contiguous in exact lane order: attention reads
// it with one fully-coalesced dwordx4 per frag. Value at (lane ln,quad; j) =
// V[key = ck*64 + kb2*32 + quad*8 + j][d = nb*16 + ln]  (B-layout of PV MFMA).
__global__ __launch_bounds__(256) void build_vt2(
    const ushort* __restrict__ kv, ushort* __restrict__ vt2) {
    __shared__ ushort Vl[64 * 136];   // [key][d], stride 136 breaks bank conflicts
    const int ck = blockIdx.x, h = blockIdx.y;
    const int tid = threadIdx.x;
    const int lane = tid & 63, wv = tid >> 6;
    #pragma unroll
    for (int rr = 0; rr < 4; ++rr) {
        int n = rr * 256 + tid;
        int key = n >> 4, part = n & 15;
        short8 v = *(const short8*)(kv + (size_t)(ck * 64 + key) * KVW + h * KVD + DN + part * 8);
        *(short8*)&Vl[key * 136 + part * 8] = v;
    }
    __syncthreads();
    const int ln = lane & 15, quad = lane >> 4;
    ushort* dst = vt2 + (((size_t)h * 32 + ck) * 16) * 512;
    #pragma unroll
    for (int w = 0; w < 4; ++w) {
        int idx2 = wv * 4 + w;
        int kb2 = idx2 >> 3, nb = idx2 & 7;
        short8 v;
        #pragma unroll
        for (int j = 0; j < 8; ++j)
            ((ushort*)&v)[j] = Vl[(kb2 * 32 + quad * 8 + j) * 136 + nb * 16 + ln];
        *(short8*)(dst + (size_t)idx2 * 512 + lane * 8) = v;
    }
}

// ---------------- split-K MFMA flash attention ----------------
// grid (seg, bq(reversed), h); block = 4 waves x 16 q-rows; 64-key chunks.
// K staged in swizzled LDS; V frags loaded coalesced from frag-ordered vt2.
__global__ __launch_bounds__(256, 4) void attn_mfma2(
    const ushort* __restrict__ qbf, const ushort* __restrict__ kf,
    const ushort* __restrict__ vt2, ushort* __restrict__ opart,
    float* __restrict__ ml) {
    const int seg = blockIdx.x, bq = 31 - blockIdx.y, h = blockIdx.z;
    if ((seg << 3) > bq) return;   // causal: segment starts beyond q-tile

    __shared__ ushort Kt[6 * 64 * 32];           // 24576 B
    __shared__ ushort Pt[4][16 * PT_STRIDE];     // 9216 B

    const int tid = threadIdx.x, lane = tid & 63, wl = tid >> 6;
    const int ln = lane & 15, quad = lane >> 4;
    const int qw = bq * 64 + wl * 16;
    const int kstart = seg * SEGK;
    const int kend = min(kstart + SEGK, bq * 64 + 64);
    const int nch = (kend - kstart) >> 6;
    const float scale = 0.07216878364870322f;  // 1/sqrt(192)

    short8 aq[6];
    const ushort* qrow = qbf + (size_t)(qw + ln) * QW + h * DQ;
    #pragma unroll
    for (int kb = 0; kb < 6; ++kb)
        aq[kb] = *(const short8*)(qrow + kb * 32 + quad * 8);

    const ushort* kfh = kf + (size_t)h * SS * 192;
    const ushort* vth2 = vt2 + ((size_t)h * 32 * 16) * 512 + lane * 8;

    // K staging: key = tid>>2, 16B part = tid&3 (xor-swizzled at source), kb = i
    const int key_s = tid >> 2;
    const int swp = ((tid & 3) ^ ((tid >> 3) & 3)) * 8;
    const ushort* kg = kfh + (size_t)(kstart + key_s) * 192 + swp;
    ushort* kdst = Kt + tid * 8;
    const int swq = (quad ^ ((ln >> 1) & 3)) * 8;   // swizzled read part

    f32x4 oacc[8];
    #pragma unroll
    for (int f = 0; f < 8; ++f) oacc[f] = (f32x4){0.f, 0.f, 0.f, 0.f};
    float mrow[4] = {-INFINITY, -INFINITY, -INFINITY, -INFINITY};
    float lrow[4] = {0.f, 0.f, 0.f, 0.f};

    for (int c = 0; c < nch; ++c) {
        const int k0 = kstart + (c << 6);
        #pragma unroll
        for (int i = 0; i < 6; ++i)
            async16(kg + i * 32, kdst + i * 2048);
        kg += 64 * 192;
        __syncthreads();

        if (k0 <= qw + 15) {
            const ushort* vfr = vth2 + (size_t)(k0 >> 6) * 16 * 512;
            // ---- V frags kb2=0: coalesced, issued early (latency under QK+softmax) ----
            short8 bv0[8];
            #pragma unroll
            for (int nb = 0; nb < 8; ++nb)
                bv0[nb] = *(const short8*)(vfr + (size_t)nb * 512);
            // ---- S = Q K^T (4 n-subtiles x 6 k-blocks) ----
            f32x4 s[4];
            #pragma unroll
            for (int ns = 0; ns < 4; ++ns) s[ns] = (f32x4){0.f, 0.f, 0.f, 0.f};
            #pragma unroll
            for (int ns = 0; ns < 4; ++ns)
                #pragma unroll
                for (int kb = 0; kb < 6; ++kb) {
                    short8 bk = *(const short8*)&Kt[(kb * 64 + ns * 16 + ln) * 32 + swq];
                    s[ns] = __builtin_amdgcn_mfma_f32_16x16x32_bf16(aq[kb], bk, s[ns], 0, 0, 0);
                }
            // ---- mask + online softmax (row = quad*4+r, col = ns*16+ln) ----
            float pv[4][4], rmax[4];
            #pragma unroll
            for (int r = 0; r < 4; ++r) rmax[r] = -1e30f;
            #pragma unroll
            for (int ns = 0; ns < 4; ++ns)
                #pragma unroll
                for (int r = 0; r < 4; ++r) {
                    int key = k0 + ns * 16 + ln;
                    int qr = qw + quad * 4 + r;
                    float v = s[ns][r] * scale;
                    if (key > qr) v = -1e30f;
                    pv[ns][r] = v;
                    rmax[r] = fmaxf(rmax[r], v);
                }
            #pragma unroll
            for (int off = 8; off; off >>= 1)
                #pragma unroll
                for (int r = 0; r < 4; ++r)
                    rmax[r] = fmaxf(rmax[r], __shfl_xor(rmax[r], off));
            float alpha[4], psum[4];
            #pragma unroll
            for (int r = 0; r < 4; ++r) {
                float mnew = fmaxf(mrow[r], rmax[r]);
                alpha[r] = __expf(mrow[r] - mnew);
                mrow[r] = mnew;
            }
            #pragma unroll
            for (int ns = 0; ns < 4; ++ns)
                #pragma unroll
                for (int r = 0; r < 4; ++r)
                    pv[ns][r] = __expf(pv[ns][r] - mrow[r]);
            #pragma unroll
            for (int r = 0; r < 4; ++r)
                psum[r] = (pv[0][r] + pv[1][r]) + (pv[2][r] + pv[3][r]);
            #pragma unroll
            for (int off = 8; off; off >>= 1)
                #pragma unroll
                for (int r = 0; r < 4; ++r)
                    psum[r] += __shfl_xor(psum[r], off);
            #pragma unroll
            for (int r = 0; r < 4; ++r) lrow[r] = lrow[r] * alpha[r] + psum[r];
            #pragma unroll
            for (int f = 0; f < 8; ++f)
                #pragma unroll
                for (int r = 0; r < 4; ++r) oacc[f][r] *= alpha[r];
            // ---- P -> LDS (per-wave, row-major [row][key], stride 72) ----
            #pragma unroll
            for (int ns = 0; ns < 4; ++ns)
                #pragma unroll
                for (int r = 0; r < 4; ++r)
                    Pt[wl][(quad * 4 + r) * PT_STRIDE + ns * 16 + ln] = f2b(pv[ns][r]);
            // ---- V frags kb2=1 ----
            short8 bv1[8];
            #pragma unroll
            for (int nb = 0; nb < 8; ++nb)
                bv1[nb] = *(const short8*)(vfr + (size_t)(8 + nb) * 512);
            // ---- O += P V ----
            short8 pa0 = *(const short8*)&Pt[wl][ln * PT_STRIDE + quad * 8];
            short8 pa1 = *(const short8*)&Pt[wl][ln * PT_STRIDE + 32 + quad * 8];
            #pragma unroll
            for (int nb = 0; nb < 8; ++nb)
                oacc[nb] = __builtin_amdgcn_mfma_f32_16x16x32_bf16(pa0, bv0[nb], oacc[nb], 0, 0, 0);
            #pragma unroll
            for (int nb = 0; nb < 8; ++nb)
                oacc[nb] = __builtin_amdgcn_mfma_f32_16x16x32_bf16(pa1, bv1[nb], oacc[nb], 0, 0, 0);
        }
        __syncthreads();
    }

    // ---- store unnormalized partial O (bf16) + m,l ----
    const size_t pbase = (((size_t)h * 32 + bq) * NSEG + seg) * 64;
    #pragma unroll
    for (int nb = 0; nb < 8; ++nb)
        #pragma unroll
        for (int r = 0; r < 4; ++r)
            opart[(pbase + wl * 16 + quad * 4 + r) * 128 + nb * 16 + ln] = f2b(oacc[nb][r]);
    if (ln == 0) {
        #pragma unroll
        for (int r = 0; r < 4; ++r) {
            ml[(pbase + wl * 16 + quad * 4 + r) * 2]     = mrow[r];
            ml[(pbase + wl * 16 + quad * 4 + r) * 2 + 1] = lrow[r];
        }
    }
}

// ---------------- merge partials -> obf ----------------
__global__ __launch_bounds__(256) void merge_attn(
    const ushort* __restrict__ opart, const float* __restrict__ ml,
    ushort* __restrict__ obf) {
    const int q = blockIdx.x;
    const int bq = q >> 6, row = q & 63, smax = bq >> 3;
    const int t = threadIdx.x;
    #pragma unroll
    for (int pp = 0; pp < 8; ++pp) {
        int idx = pp * 256 + t;            // 0..2047 = h*128 + d
        int h = idx >> 7, d = idx & 127;
        size_t rbase = (((size_t)h * 32 + bq) * NSEG) * 64 + row;  // + s*64
        float M = -1e30f;
        for (int s = 0; s <= smax; ++s)
            M = fmaxf(M, ml[(rbase + (size_t)s * 64) * 2]);
        float L = 0.f, acc = 0.f;
        for (int s = 0; s <= smax; ++s) {
            size_t ri = rbase + (size_t)s * 64;
            float w = __expf(ml[ri * 2] - M);
            L += w * ml[ri * 2 + 1];
            acc += w * b2f(opart[ri * 128 + d]);
        }
        obf[(size_t)q * OW + h * DV + d] = f2b(acc / L);
    }
}

// ---------------- launch ----------------
extern "C" void kernel_launch(void* const* d_in, const int* in_sizes, int n_in,
                              void* d_out, int out_size, void* d_ws, size_t ws_size,
                              hipStream_t stream) {
    const void* x       = d_in[0];
    const void* w_q_a   = d_in[1];
    const void* q_a_ln  = d_in[2];
    const void* w_q_b   = d_in[3];
    const void* w_kv_a  = d_in[4];
    const void* kv_a_ln = d_in[5];
    const void* w_kv_b  = d_in[6];
    const void* w_out   = d_in[7];

    char* ws = (char*)d_ws;
    int*    flag  = (int*)ws;
    ushort* qbf   = (ushort*)(ws + 256);             // S*QW
    ushort* obf   = qbf   + (size_t)SS * QW;         // S*OW
    ushort* wqat  = obf   + (size_t)SS * OW;         // QLAT*EE
    ushort* wkvat = wqat  + (size_t)QLAT * EE;       // CKVW*EE
    ushort* wqbt  = wkvat + (size_t)CKVW * EE;       // QW*QLAT
    ushort* wkvbt = wqbt  + (size_t)QW * QLAT;       // KVW*KLAT
    ushort* woutt = wkvbt + (size_t)KVW * KLAT;      // EE*OW
    ushort* kf    = woutt + (size_t)EE * OW;         // HH*SS*192
    ushort* vt2   = kf    + (size_t)HH * SS * 192;   // HH*SS*DV (frag-ordered)
    float*  ml    = (float*)(vt2 + (size_t)HH * SS * DV);  // HH*32*NSEG*64*2 floats
    // overlay zone (all dead before attention writes opart):
    ushort* ckvbf = (ushort*)(ml + (size_t)HH * 32 * NSEG * 64 * 2);  // S*CKVW
    ushort* qa_bf = ckvbf + (size_t)SS * CKVW;       // S*QLAT
    ushort* xbf   = qa_bf + (size_t)SS * QLAT;       // S*EE
    ushort* kvbf  = xbf   + (size_t)SS * EE;         // S*KVW
    ushort* kpebf = kvbf  + (size_t)SS * KVW;        // S*DR
    ushort* opart = ckvbf;  // HH*32*NSEG*64*128 halfs <= overlay span (17.04M)

    detect_dtype<<<1, 1, 0, stream>>>((const unsigned int*)q_a_ln, flag);

    conv_x_bf<<<(SS * EE / 4 + 255) / 256, 256, 0, stream>>>(x, xbf, SS * EE, flag);
    transpose_bf<<<dim3(QLAT / 32, EE / 32), 256, 0, stream>>>(w_q_a, wqat, EE, QLAT, flag);
    transpose_bf<<<dim3(CKVW / 32, EE / 32), 256, 0, stream>>>(w_kv_a, wkvat, EE, CKVW, flag);
    transpose_bf<<<dim3(QW / 32, QLAT / 32), 256, 0, stream>>>(w_q_b, wqbt, QLAT, QW, flag);
    transpose_bf<<<dim3(KVW / 32, KLAT / 32), 256, 0, stream>>>(w_kv_b, wkvbt, KLAT, KVW, flag);
    transpose_bf<<<dim3(EE / 32, OW / 32), 256, 0, stream>>>(w_out, woutt, OW, EE, flag);

    // qa_bf = x @ w_q_a  (2048x1536, K=2048)
    gemm_bf<<<dim3(QLAT / 128, SS / 128), 256, 0, stream>>>(
        xbf, wqat, qa_bf, QLAT, EE, EE, EE, QLAT, 1, nullptr);
    // ckvbf = x @ w_kv_a (2048x576, K=2048)
    gemm_bf<<<dim3((CKVW + 127) / 128, SS / 128), 256, 0, stream>>>(
        xbf, wkvat, ckvbf, CKVW, EE, EE, EE, CKVW, 1, nullptr);

    rmsnorm_bf<<<SS, 256, 0, stream>>>(qa_bf, q_a_ln, QLAT, QLAT, flag);
    rmsnorm_bf<<<SS, 256, 0, stream>>>(ckvbf, kv_a_ln, KLAT, CKVW, flag);

    // qbf = qa_norm @ w_q_b (2048x3072, K=1536)
    gemm_bf<<<dim3(QW / 128, SS / 128), 256, 0, stream>>>(
        qa_bf, wqbt, qbf, QW, QLAT, QLAT, QLAT, QW, 1, nullptr);
    // kvbf = ckv_norm @ w_kv_b (2048x4096, K=512)
    gemm_bf<<<dim3(KVW / 128, SS / 128), 256, 0, stream>>>(
        ckvbf, wkvbt, kvbf, KVW, KLAT, CKVW, KLAT, KVW, 1, nullptr);

    rope_q_bf<<<(SS * HH + 255) / 256, 256, 0, stream>>>(qbf);
    rope_k_bf<<<(SS + 63) / 64, 64, 0, stream>>>(ckvbf, kpebf);

    build_kf<<<SS * HH * 24 / 256, 256, 0, stream>>>(kvbf, kpebf, kf);
    build_vt2<<<dim3(SS / 64, HH), 256, 0, stream>>>(kvbf, vt2);

    attn_mfma2<<<dim3(NSEG, SS / 64, HH), 256, 0, stream>>>(qbf, kf, vt2, opart, ml);
    merge_attn<<<SS, 256, 0, stream>>>(opart, ml, obf);

    // out = o @ w_out (2048x2048, K=2048)
    gemm_bf<<<dim3(EE / 128, SS / 128), 256, 0, stream>>>(
        obf, woutt, d_out, EE, OW, OW, OW, EE, 2, flag);
}

// Round 7
// 455.222 us; speedup vs baseline: 1.1902x; 1.0494x over previous
//
#include <hip/hip_runtime.h>
#include <hip/hip_bf16.h>
#include <math.h>

// Problem constants (fixed shapes)
#define SS   2048   // sequence length
#define EE   2048   // embed dim
#define HH   16     // heads
#define QLAT 1536   // q latent
#define KLAT 512    // kv latent
#define DN   128
#define DR   64
#define DV   128
#define DQ   192    // DN+DR
#define KVD  256    // DN+DV
#define CKVW 576    // KLAT+DR
#define QW   3072   // HH*DQ
#define KVW  4096   // HH*KVD
#define OW   2048   // HH*DV
#define QAC  2112   // QLAT + CKVW (merged a-proj output width)

#define NSEG 4      // key segments (flash-decoding split)
#define SEGK 512    // keys per segment
#define PT_STRIDE 72

typedef __attribute__((ext_vector_type(8))) short short8;
typedef __attribute__((ext_vector_type(4))) float f32x4;

// ---------------- helpers ----------------
__global__ void detect_dtype(const unsigned int* __restrict__ lnw, int* flag) {
    *flag = (lnw[0] == 0x3F803F80u) ? 1 : 0;  // bf16 pair of 1.0 vs fp32 1.0
}

__device__ __forceinline__ float ld_in(const void* p, size_t i, int bf) {
    if (bf) return __bfloat162float(((const __hip_bfloat16*)p)[i]);
    return ((const float*)p)[i];
}

__device__ __forceinline__ ushort f2b(float v) {
    __hip_bfloat16 b = __float2bfloat16(v);
    return *(ushort*)&b;
}
__device__ __forceinline__ float b2f(ushort u) {
    __hip_bfloat16 b = *(__hip_bfloat16*)&u;
    return __bfloat162float(b);
}

// async global->LDS, 16 B per lane; LDS dst must be wave-uniform base + lane*16
__device__ __forceinline__ void async16(const ushort* g, ushort* l) {
    __builtin_amdgcn_global_load_lds(
        (const __attribute__((address_space(1))) void*)g,
        (__attribute__((address_space(3))) void*)l, 16, 0, 0);
}

// ---------------- input convert (x -> bf16) ----------------
__global__ __launch_bounds__(256) void conv_x_bf(
    const void* __restrict__ src, ushort* __restrict__ dst, int n, const int* flag) {
    const int bf = *flag;
    int i = (blockIdx.x * 256 + threadIdx.x) * 4;
    if (i >= n) return;
    ushort4 u;
    u.x = f2b(ld_in(src, i + 0, bf));
    u.y = f2b(ld_in(src, i + 1, bf));
    u.z = f2b(ld_in(src, i + 2, bf));
    u.w = f2b(ld_in(src, i + 3, bf));
    *(ushort4*)(dst + i) = u;
}

// ---------------- weight transpose+convert: in[R][C] -> out[C][R] bf16 ----------------
// 64x64 tiles; LDS stride 66 ushorts -> lane dword-stride 33 (conflict-free);
// ushort2 stores give 128 B contiguous segments per output row.
__global__ __launch_bounds__(256) void transpose_bf(
    const void* __restrict__ in, ushort* __restrict__ out,
    int R, int C, const int* flag) {
    const int bf = *flag;
    __shared__ ushort t[64][66];
    const int c0 = blockIdx.x * 64, r0 = blockIdx.y * 64;
    const int lane = threadIdx.x & 63, grp = threadIdx.x >> 6;
    #pragma unroll
    for (int p = 0; p < 16; ++p) {
        int r = p * 4 + grp;
        t[lane][r] = f2b(ld_in(in, (size_t)(r0 + r) * C + c0 + lane, bf));
    }
    __syncthreads();
    const int ro = (threadIdx.x & 31) * 2, co = threadIdx.x >> 5;
    #pragma unroll
    for (int p = 0; p < 8; ++p) {
        int c = p * 8 + co;
        ushort2 u = *(const ushort2*)&t[c][ro];
        *(ushort2*)&out[(size_t)(c0 + c) * R + r0 + ro] = u;
    }
}

// ---------------- bf16 MFMA GEMM 128x128: C[M][N] = A[M][K] @ Bt[N][K]^T ----------------
// XOR-swizzled LDS: 16B part p of row r stored at p^((r>>1)&3).
__global__ __launch_bounds__(256) void gemm_bf(
    const ushort* __restrict__ A, const ushort* __restrict__ Bt,
    void* __restrict__ C, int N, int K, int lda, int ldb, int ldc,
    int cmode, const int* __restrict__ cflag) {
    __shared__ ushort As[128 * 32];
    __shared__ ushort Bs[128 * 32];
    const int tid = threadIdx.x;
    const int bm = blockIdx.y * 128, bn = blockIdx.x * 128;
    const int lane = tid & 63, wv = tid >> 6;
    const int wm = (wv & 1) * 64, wn = (wv >> 1) * 64;
    const int ln = lane & 15, quad = lane >> 4;

    f32x4 acc[4][4];
    #pragma unroll
    for (int i = 0; i < 4; ++i)
        #pragma unroll
        for (int j = 0; j < 4; ++j) acc[i][j] = (f32x4){0.f, 0.f, 0.f, 0.f};

    const int srow = tid >> 2;
    const int spart = (((tid & 3) ^ ((tid >> 3) & 3))) * 8;  // swizzled source 16B part
    const ushort* Ag0 = A  + (size_t)(bm + srow) * lda + spart;
    const ushort* Ag1 = Ag0 + (size_t)64 * lda;
    const ushort* Bg0 = Bt + (size_t)(bn + srow) * ldb + spart;
    const ushort* Bg1 = Bg0 + (size_t)64 * ldb;
    ushort* Asl = As + tid * 8;
    ushort* Bsl = Bs + tid * 8;
    const bool bok0 = (bn + srow) < N;
    const bool bok1 = (bn + 64 + srow) < N;
    const int swq = (quad ^ ((ln >> 1) & 3)) * 8;  // swizzled read part

    for (int k0 = 0; k0 < K; k0 += 32) {
        async16(Ag0 + k0, Asl);
        async16(Ag1 + k0, Asl + 2048);
        if (bok0) async16(Bg0 + k0, Bsl);
        if (bok1) async16(Bg1 + k0, Bsl + 2048);
        __syncthreads();
        short8 af[4], bfr[4];
        #pragma unroll
        for (int t = 0; t < 4; ++t) {
            af[t]  = *(const short8*)&As[(wm + t * 16 + ln) * 32 + swq];
            bfr[t] = *(const short8*)&Bs[(wn + t * 16 + ln) * 32 + swq];
        }
        #pragma unroll
        for (int i = 0; i < 4; ++i)
            #pragma unroll
            for (int j = 0; j < 4; ++j)
                acc[i][j] = __builtin_amdgcn_mfma_f32_16x16x32_bf16(af[i], bfr[j], acc[i][j], 0, 0, 0);
        __syncthreads();
    }

    const int cbf = (cmode == 2) ? *cflag : cmode;
    #pragma unroll
    for (int i = 0; i < 4; ++i) {
        #pragma unroll
        for (int r = 0; r < 4; ++r) {
            const int m = bm + wm + i * 16 + quad * 4 + r;
            #pragma unroll
            for (int j = 0; j < 4; ++j) {
                const int n = bn + wn + j * 16 + ln;
                if (n < N) {
                    if (cbf) ((ushort*)C)[(size_t)m * ldc + n] = f2b(acc[i][j][r]);
                    else     ((float*)C)[(size_t)m * ldc + n] = acc[i][j][r];
                }
            }
        }
    }
}

// ---------------- bf16 MFMA GEMM 64x128 (small-grid variant) ----------------
// 2x2 waves, each 32x64 (2x4 MFMAs). ~12 KB LDS -> ~5 blocks/CU for
// small grids where the 128x128 tile leaves CUs idle (<=1 block/CU).
__global__ __launch_bounds__(256) void gemm_bf64(
    const ushort* __restrict__ A, const ushort* __restrict__ Bt,
    void* __restrict__ C, int N, int K, int lda, int ldb, int ldc,
    int cmode, const int* __restrict__ cflag) {
    __shared__ ushort As[64 * 32];
    __shared__ ushort Bs[128 * 32];
    const int tid = threadIdx.x;
    const int bm = blockIdx.y * 64, bn = blockIdx.x * 128;
    const int lane = tid & 63, wv = tid >> 6;
    const int wm = (wv & 1) * 32, wn = (wv >> 1) * 64;
    const int ln = lane & 15, quad = lane >> 4;

    f32x4 acc[2][4];
    #pragma unroll
    for (int i = 0; i < 2; ++i)
        #pragma unroll
        for (int j = 0; j < 4; ++j) acc[i][j] = (f32x4){0.f, 0.f, 0.f, 0.f};

    const int srow = tid >> 2;
    const int spart = (((tid & 3) ^ ((tid >> 3) & 3))) * 8;
    const ushort* Ag0 = A  + (size_t)(bm + srow) * lda + spart;
    const ushort* Bg0 = Bt + (size_t)(bn + srow) * ldb + spart;
    const ushort* Bg1 = Bg0 + (size_t)64 * ldb;
    ushort* Asl = As + tid * 8;
    ushort* Bsl = Bs + tid * 8;
    const bool bok0 = (bn + srow) < N;
    const bool bok1 = (bn + 64 + srow) < N;
    const int swq = (quad ^ ((ln >> 1) & 3)) * 8;

    for (int k0 = 0; k0 < K; k0 += 32) {
        async16(Ag0 + k0, Asl);
        if (bok0) async16(Bg0 + k0, Bsl);
        if (bok1) async16(Bg1 + k0, Bsl + 2048);
        __syncthreads();
        short8 af[2], bfr[4];
        #pragma unroll
        for (int t = 0; t < 2; ++t)
            af[t] = *(const short8*)&As[(wm + t * 16 + ln) * 32 + swq];
        #pragma unroll
        for (int t = 0; t < 4; ++t)
            bfr[t] = *(const short8*)&Bs[(wn + t * 16 + ln) * 32 + swq];
        #pragma unroll
        for (int i = 0; i < 2; ++i)
            #pragma unroll
            for (int j = 0; j < 4; ++j)
                acc[i][j] = __builtin_amdgcn_mfma_f32_16x16x32_bf16(af[i], bfr[j], acc[i][j], 0, 0, 0);
        __syncthreads();
    }

    const int cbf = (cmode == 2) ? *cflag : cmode;
    #pragma unroll
    for (int i = 0; i < 2; ++i) {
        #pragma unroll
        for (int r = 0; r < 4; ++r) {
            const int m = bm + wm + i * 16 + quad * 4 + r;
            #pragma unroll
            for (int j = 0; j < 4; ++j) {
                const int n = bn + wn + j * 16 + ln;
                if (n < N) {
                    if (cbf) ((ushort*)C)[(size_t)m * ldc + n] = f2b(acc[i][j][r]);
                    else     ((float*)C)[(size_t)m * ldc + n] = acc[i][j][r];
                }
            }
        }
    }
}

// ---------------- RMSNorm bf16 in-place (fp32 math) ----------------
__global__ __launch_bounds__(256) void rmsnorm_bf(
    ushort* __restrict__ x, const void* __restrict__ w,
    int cols, int stride, const int* wflag) {
    const int wbf = *wflag;
    ushort* p = x + (size_t)blockIdx.x * stride;
    float ss = 0.f;
    for (int i = threadIdx.x; i < cols; i += 256) { float v = b2f(p[i]); ss += v * v; }
    #pragma unroll
    for (int off = 32; off; off >>= 1) ss += __shfl_xor(ss, off);
    __shared__ float red[4];
    const int wid = threadIdx.x >> 6, lane = threadIdx.x & 63;
    if (lane == 0) red[wid] = ss;
    __syncthreads();
    const float tot = red[0] + red[1] + red[2] + red[3];
    const float scale = rsqrtf(tot / (float)cols + 1e-6f);
    for (int i = threadIdx.x; i < cols; i += 256)
        p[i] = f2b(b2f(p[i]) * scale * ld_in(w, i, wbf));
}

// ---------------- RoPE (fp32 math on bf16 data) ----------------
__device__ __forceinline__ void rope64(const float* in, float t, float* out) {
    #pragma unroll
    for (int i = 0; i < 32; ++i) {
        float inv = powf(10000.0f, -(float)i / 32.0f);
        float sv, cv;
        sincosf(t * inv, &sv, &cv);
        float x0 = in[2 * i], x1 = in[2 * i + 1];
        out[i]      = x0 * cv - x1 * sv;
        out[i + 32] = x1 * cv + x0 * sv;
    }
}

__global__ void rope_q_bf(ushort* __restrict__ q) {
    int idx = blockIdx.x * blockDim.x + threadIdx.x;
    if (idx >= SS * HH) return;
    int s = idx >> 4, h = idx & 15;
    ushort* p = q + (size_t)s * QW + h * DQ + DN;
    float buf[DR], out[DR];
    #pragma unroll
    for (int i = 0; i < DR; ++i) buf[i] = b2f(p[i]);
    rope64(buf, (float)s, out);
    #pragma unroll
    for (int i = 0; i < DR; ++i) p[i] = f2b(out[i]);
}

__global__ void rope_k_bf(const ushort* __restrict__ ckv, ushort* __restrict__ kpe,
                          int stride) {
    int s = blockIdx.x * blockDim.x + threadIdx.x;
    if (s >= SS) return;
    const ushort* p = ckv + (size_t)s * stride + KLAT;
    float buf[DR], out[DR];
    #pragma unroll
    for (int i = 0; i < DR; ++i) buf[i] = b2f(p[i]);
    rope64(buf, (float)s, out);
    ushort* dp = kpe + (size_t)s * DR;
    #pragma unroll
    for (int i = 0; i < DR; ++i) dp[i] = f2b(out[i]);
}

// ---------------- build head-major K-full: kf[h][s][192] ----------------
__global__ __launch_bounds__(256) void build_kf(
    const ushort* __restrict__ kv, const ushort* __restrict__ kpe,
    ushort* __restrict__ kf) {
    int idx = blockIdx.x * 256 + threadIdx.x;       // SS*HH*24 items
    int part = idx % 24;
    int rest = idx / 24;
    int h = rest & 15, s = rest >> 4;
    short8 v;
    if (part < 16) v = *(const short8*)(kv + (size_t)s * KVW + h * KVD + part * 8);
    else           v = *(const short8*)(kpe + (size_t)s * DR + (part - 16) * 8);
    *(short8*)(kf + ((size_t)h * SS + s) * 192 + part * 8) = v;
}

// ---------------- build frag-ordered V: vt2[h][ck][idx2=kb2*8+nb][lane][8] ----------------
__global__ __launch_bounds__(256) void build_vt2(
    const ushort* __restrict__ kv, ushort* __restrict__ vt2) {
    __shared__ ushort Vl[64 * 136];
    const int ck = blockIdx.x, h = blockIdx.y;
    const int tid = threadIdx.x;
    const int lane = tid & 63, wv = tid >> 6;
    #pragma unroll
    for (int rr = 0; rr < 4; ++rr) {
        int n = rr * 256 + tid;
        int key = n >> 4, part = n & 15;
        short8 v = *(const short8*)(kv + (size_t)(ck * 64 + key) * KVW + h * KVD + DN + part * 8);
        *(short8*)&Vl[key * 136 + part * 8] = v;
    }
    __syncthreads();
    const int ln = lane & 15, quad = lane >> 4;
    ushort* dst = vt2 + (((size_t)h * 32 + ck) * 16) * 512;
    #pragma unroll
    for (int w = 0; w < 4; ++w) {
        int idx2 = wv * 4 + w;
        int kb2 = idx2 >> 3, nb = idx2 & 7;
        short8 v;
        #pragma unroll
        for (int j = 0; j < 8; ++j)
            ((ushort*)&v)[j] = Vl[(kb2 * 32 + quad * 8 + j) * 136 + nb * 16 + ln];
        *(short8*)(dst + (size_t)idx2 * 512 + lane * 8) = v;
    }
}

// ---------------- split-K MFMA flash attention ----------------
__global__ __launch_bounds__(256, 4) void attn_mfma2(
    const ushort* __restrict__ qbf, const ushort* __restrict__ kf,
    const ushort* __restrict__ vt2, ushort* __restrict__ opart,
    float* __restrict__ ml) {
    const int seg = blockIdx.x, bq = 31 - blockIdx.y, h = blockIdx.z;
    if ((seg << 3) > bq) return;   // causal: segment starts beyond q-tile

    __shared__ ushort Kt[6 * 64 * 32];           // 24576 B
    __shared__ ushort Pt[4][16 * PT_STRIDE];     // 9216 B

    const int tid = threadIdx.x, lane = tid & 63, wl = tid >> 6;
    const int ln = lane & 15, quad = lane >> 4;
    const int qw = bq * 64 + wl * 16;
    const int kstart = seg * SEGK;
    const int kend = min(kstart + SEGK, bq * 64 + 64);
    const int nch = (kend - kstart) >> 6;
    const float scale = 0.07216878364870322f;  // 1/sqrt(192)

    short8 aq[6];
    const ushort* qrow = qbf + (size_t)(qw + ln) * QW + h * DQ;
    #pragma unroll
    for (int kb = 0; kb < 6; ++kb)
        aq[kb] = *(const short8*)(qrow + kb * 32 + quad * 8);

    const ushort* kfh = kf + (size_t)h * SS * 192;
    const ushort* vth2 = vt2 + ((size_t)h * 32 * 16) * 512 + lane * 8;

    const int key_s = tid >> 2;
    const int swp = ((tid & 3) ^ ((tid >> 3) & 3)) * 8;
    const ushort* kg = kfh + (size_t)(kstart + key_s) * 192 + swp;
    ushort* kdst = Kt + tid * 8;
    const int swq = (quad ^ ((ln >> 1) & 3)) * 8;

    f32x4 oacc[8];
    #pragma unroll
    for (int f = 0; f < 8; ++f) oacc[f] = (f32x4){0.f, 0.f, 0.f, 0.f};
    float mrow[4] = {-INFINITY, -INFINITY, -INFINITY, -INFINITY};
    float lrow[4] = {0.f, 0.f, 0.f, 0.f};

    for (int c = 0; c < nch; ++c) {
        const int k0 = kstart + (c << 6);
        #pragma unroll
        for (int i = 0; i < 6; ++i)
            async16(kg + i * 32, kdst + i * 2048);
        kg += 64 * 192;
        __syncthreads();

        if (k0 <= qw + 15) {
            const ushort* vfr = vth2 + (size_t)(k0 >> 6) * 16 * 512;
            short8 bv0[8];
            #pragma unroll
            for (int nb = 0; nb < 8; ++nb)
                bv0[nb] = *(const short8*)(vfr + (size_t)nb * 512);
            f32x4 s[4];
            #pragma unroll
            for (int ns = 0; ns < 4; ++ns) s[ns] = (f32x4){0.f, 0.f, 0.f, 0.f};
            #pragma unroll
            for (int ns = 0; ns < 4; ++ns)
                #pragma unroll
                for (int kb = 0; kb < 6; ++kb) {
                    short8 bk = *(const short8*)&Kt[(kb * 64 + ns * 16 + ln) * 32 + swq];
                    s[ns] = __builtin_amdgcn_mfma_f32_16x16x32_bf16(aq[kb], bk, s[ns], 0, 0, 0);
                }
            float pv[4][4], rmax[4];
            #pragma unroll
            for (int r = 0; r < 4; ++r) rmax[r] = -1e30f;
            #pragma unroll
            for (int ns = 0; ns < 4; ++ns)
                #pragma unroll
                for (int r = 0; r < 4; ++r) {
                    int key = k0 + ns * 16 + ln;
                    int qr = qw + quad * 4 + r;
                    float v = s[ns][r] * scale;
                    if (key > qr) v = -1e30f;
                    pv[ns][r] = v;
                    rmax[r] = fmaxf(rmax[r], v);
                }
            #pragma unroll
            for (int off = 8; off; off >>= 1)
                #pragma unroll
                for (int r = 0; r < 4; ++r)
                    rmax[r] = fmaxf(rmax[r], __shfl_xor(rmax[r], off));
            float alpha[4], psum[4];
            #pragma unroll
            for (int r = 0; r < 4; ++r) {
                float mnew = fmaxf(mrow[r], rmax[r]);
                alpha[r] = __expf(mrow[r] - mnew);
                mrow[r] = mnew;
            }
            #pragma unroll
            for (int ns = 0; ns < 4; ++ns)
                #pragma unroll
                for (int r = 0; r < 4; ++r)
                    pv[ns][r] = __expf(pv[ns][r] - mrow[r]);
            #pragma unroll
            for (int r = 0; r < 4; ++r)
                psum[r] = (pv[0][r] + pv[1][r]) + (pv[2][r] + pv[3][r]);
            #pragma unroll
            for (int off = 8; off; off >>= 1)
                #pragma unroll
                for (int r = 0; r < 4; ++r)
                    psum[r] += __shfl_xor(psum[r], off);
            #pragma unroll
            for (int r = 0; r < 4; ++r) lrow[r] = lrow[r] * alpha[r] + psum[r];
            #pragma unroll
            for (int f = 0; f < 8; ++f)
                #pragma unroll
                for (int r = 0; r < 4; ++r) oacc[f][r] *= alpha[r];
            #pragma unroll
            for (int ns = 0; ns < 4; ++ns)
                #pragma unroll
                for (int r = 0; r < 4; ++r)
                    Pt[wl][(quad * 4 + r) * PT_STRIDE + ns * 16 + ln] = f2b(pv[ns][r]);
            short8 bv1[8];
            #pragma unroll
            for (int nb = 0; nb < 8; ++nb)
                bv1[nb] = *(const short8*)(vfr + (size_t)(8 + nb) * 512);
            short8 pa0 = *(const short8*)&Pt[wl][ln * PT_STRIDE + quad * 8];
            short8 pa1 = *(const short8*)&Pt[wl][ln * PT_STRIDE + 32 + quad * 8];
            #pragma unroll
            for (int nb = 0; nb < 8; ++nb)
                oacc[nb] = __builtin_amdgcn_mfma_f32_16x16x32_bf16(pa0, bv0[nb], oacc[nb], 0, 0, 0);
            #pragma unroll
            for (int nb = 0; nb < 8; ++nb)
                oacc[nb] = __builtin_amdgcn_mfma_f32_16x16x32_bf16(pa1, bv1[nb], oacc[nb], 0, 0, 0);
        }
        __syncthreads();
    }

    const size_t pbase = (((size_t)h * 32 + bq) * NSEG + seg) * 64;
    #pragma unroll
    for (int nb = 0; nb < 8; ++nb)
        #pragma unroll
        for (int r = 0; r < 4; ++r)
            opart[(pbase + wl * 16 + quad * 4 + r) * 128 + nb * 16 + ln] = f2b(oacc[nb][r]);
    if (ln == 0) {
        #pragma unroll
        for (int r = 0; r < 4; ++r) {
            ml[(pbase + wl * 16 + quad * 4 + r) * 2]     = mrow[r];
            ml[(pbase + wl * 16 + quad * 4 + r) * 2 + 1] = lrow[r];
        }
    }
}

// ---------------- merge partials -> obf ----------------
__global__ __launch_bounds__(256) void merge_attn(
    const ushort* __restrict__ opart, const float* __restrict__ ml,
    ushort* __restrict__ obf) {
    const int q = blockIdx.x;
    const int bq = q >> 6, row = q & 63, smax = bq >> 3;
    const int t = threadIdx.x;
    #pragma unroll
    for (int pp = 0; pp < 8; ++pp) {
        int idx = pp * 256 + t;            // 0..2047 = h*128 + d
        int h = idx >> 7, d = idx & 127;
        size_t rbase = (((size_t)h * 32 + bq) * NSEG) * 64 + row;  // + s*64
        float M = -1e30f;
        for (int s = 0; s <= smax; ++s)
            M = fmaxf(M, ml[(rbase + (size_t)s * 64) * 2]);
        float L = 0.f, acc = 0.f;
        for (int s = 0; s <= smax; ++s) {
            size_t ri = rbase + (size_t)s * 64;
            float w = __expf(ml[ri * 2] - M);
            L += w * ml[ri * 2 + 1];
            acc += w * b2f(opart[ri * 128 + d]);
        }
        obf[(size_t)q * OW + h * DV + d] = f2b(acc / L);
    }
}

// ---------------- launch ----------------
extern "C" void kernel_launch(void* const* d_in, const int* in_sizes, int n_in,
                              void* d_out, int out_size, void* d_ws, size_t ws_size,
                              hipStream_t stream) {
    const void* x       = d_in[0];
    const void* w_q_a   = d_in[1];
    const void* q_a_ln  = d_in[2];
    const void* w_q_b   = d_in[3];
    const void* w_kv_a  = d_in[4];
    const void* kv_a_ln = d_in[5];
    const void* w_kv_b  = d_in[6];
    const void* w_out   = d_in[7];

    char* ws = (char*)d_ws;
    int*    flag  = (int*)ws;
    ushort* qbf   = (ushort*)(ws + 256);             // S*QW
    ushort* obf   = qbf   + (size_t)SS * QW;         // S*OW
    ushort* wqat  = obf   + (size_t)SS * OW;         // QLAT*EE  } contiguous ->
    ushort* wkvat = wqat  + (size_t)QLAT * EE;       // CKVW*EE  } merged Bt[2112][EE]
    ushort* wqbt  = wkvat + (size_t)CKVW * EE;       // QW*QLAT
    ushort* wkvbt = wqbt  + (size_t)QW * QLAT;       // KVW*KLAT
    ushort* woutt = wkvbt + (size_t)KVW * KLAT;      // EE*OW
    ushort* kf    = woutt + (size_t)EE * OW;         // HH*SS*192
    ushort* vt2   = kf    + (size_t)HH * SS * 192;   // HH*SS*DV (frag-ordered)
    float*  ml    = (float*)(vt2 + (size_t)HH * SS * DV);  // HH*32*NSEG*64*2 floats
    // overlay zone (all dead before attention writes opart):
    ushort* qac   = (ushort*)(ml + (size_t)HH * 32 * NSEG * 64 * 2);  // S*QAC
    ushort* xbf   = qac   + (size_t)SS * QAC;        // S*EE
    ushort* kvbf  = xbf   + (size_t)SS * EE;         // S*KVW
    ushort* kpebf = kvbf  + (size_t)SS * KVW;        // S*DR
    ushort* opart = qac;  // HH*32*NSEG*64*128 halfs <= overlay span (17.04M)

    detect_dtype<<<1, 1, 0, stream>>>((const unsigned int*)q_a_ln, flag);

    conv_x_bf<<<(SS * EE / 4 + 255) / 256, 256, 0, stream>>>(x, xbf, SS * EE, flag);
    transpose_bf<<<dim3(QLAT / 64, EE / 64), 256, 0, stream>>>(w_q_a, wqat, EE, QLAT, flag);
    transpose_bf<<<dim3(CKVW / 64, EE / 64), 256, 0, stream>>>(w_kv_a, wkvat, EE, CKVW, flag);
    transpose_bf<<<dim3(QW / 64, QLAT / 64), 256, 0, stream>>>(w_q_b, wqbt, QLAT, QW, flag);
    transpose_bf<<<dim3(KVW / 64, KLAT / 64), 256, 0, stream>>>(w_kv_b, wkvbt, KLAT, KVW, flag);
    transpose_bf<<<dim3(EE / 64, OW / 64), 256, 0, stream>>>(w_out, woutt, OW, EE, flag);

    // qac = x @ [w_q_a | w_kv_a]  (2048 x 2112, K=2048), merged, 544 blocks
    gemm_bf64<<<dim3((QAC + 127) / 128, SS / 64), 256, 0, stream>>>(
        xbf, wqat, qac, QAC, EE, EE, EE, QAC, 1, nullptr);

    rmsnorm_bf<<<SS, 256, 0, stream>>>(qac, q_a_ln, QLAT, QAC, flag);
    rmsnorm_bf<<<SS, 256, 0, stream>>>(qac + QLAT, kv_a_ln, KLAT, QAC, flag);

    // qbf = qa_norm @ w_q_b (2048x3072, K=1536), A = qac cols 0..1536
    gemm_bf<<<dim3(QW / 128, SS / 128), 256, 0, stream>>>(
        qac, wqbt, qbf, QW, QLAT, QAC, QLAT, QW, 1, nullptr);
    // kvbf = ckv_norm @ w_kv_b (2048x4096, K=512), A = qac cols 1536..2048
    gemm_bf<<<dim3(KVW / 128, SS / 128), 256, 0, stream>>>(
        qac + QLAT, wkvbt, kvbf, KVW, KLAT, QAC, KLAT, KVW, 1, nullptr);

    rope_q_bf<<<(SS * HH + 255) / 256, 256, 0, stream>>>(qbf);
    rope_k_bf<<<(SS + 63) / 64, 64, 0, stream>>>(qac + QLAT, kpebf, QAC);

    build_kf<<<SS * HH * 24 / 256, 256, 0, stream>>>(kvbf, kpebf, kf);
    build_vt2<<<dim3(SS / 64, HH), 256, 0, stream>>>(kvbf, vt2);

    attn_mfma2<<<dim3(NSEG, SS / 64, HH), 256, 0, stream>>>(qbf, kf, vt2, opart, ml);
    merge_attn<<<SS, 256, 0, stream>>>(opart, ml, obf);

    // out = o @ w_out (2048x2048, K=2048), 512 blocks via 64-tile
    gemm_bf64<<<dim3(EE / 128, SS / 64), 256, 0, stream>>>(
        obf, woutt, d_out, EE, OW, OW, OW, EE, 2, flag);
}